// Round 11
// baseline (160.549 us; speedup 1.0000x reference)
//
#include <hip/hip_runtime.h>

// NTK-SVGP forward: D=H=128, C=10, N=256, M=128, T=128, sigma2=1, delta=1
#define H 128
#define DD 128
#define CC 10
#define NX 256
#define MZ 128
#define TN 128
#define S_TOT 512   // samples: X[0..255], Z[256..383], X_test[384..511]
#define SCALE (1.0f/256.0f)   // 1/(delta*N)
#define JIT 1e-3f
#define INV_S2 1.0f

// ---------------- ws layout (float offsets) ----------------
#define OFF_XS    0u
#define OFF_A1    (OFF_XS   + S_TOT*DD)
#define OFF_A2    (OFF_A1   + S_TOT*H)
#define OFF_G1    (OFF_A2   + S_TOT*H)
#define OFF_G2    (OFF_G1   + S_TOT*CC*H)
#define OFF_W2T   (OFF_G2   + S_TOT*CC*H)
#define OFF_BASE  (OFF_W2T  + H*H)
#define BASE_ZX   0u
#define BASE_ZZ   (3u*MZ*NX)
#define BASE_TZ   (3u*MZ*NX + 3u*MZ*MZ)
#define OFF_KZX   (OFF_BASE + 3u*MZ*NX + 3u*MZ*MZ + 3u*TN*MZ)
#define OFF_KZZ   (OFF_KZX  + CC*MZ*NX)
#define OFF_KXZ   (OFF_KZZ  + CC*MZ*MZ)
#define OFF_KXXD  (OFF_KXZ  + CC*TN*MZ)
#define OFF_KZZJ  (OFF_KXXD + CC*TN)
#define OFF_KZZB  (OFF_KZZJ + CC*MZ*MZ)
#define OFF_LAMU  (OFF_KZZB + CC*MZ*MZ)
#define OFF_LC    (OFF_LAMU + CC*MZ)
#define OFF_INVD  (OFF_LC   + 2u*CC*MZ*MZ)
#define OFF_YLAM  (OFF_INVD + 2u*CC*MZ)
#define OFF_SSQ   (OFF_YLAM + CC*MZ)
#define OFF_FMEAN (OFF_SSQ  + 2u*CC*TN)

__global__ __launch_bounds__(128) void k_w2t(const float* __restrict__ W2, float* __restrict__ W2T,
                                             float* __restrict__ LamU) {
  int k = blockIdx.x, h = threadIdx.x;
  W2T[k*H + h] = W2[h*H + k];
  if (k < CC) LamU[k*MZ + h] = 0.0f;   // zero for k_gram's atomic accumulation
}

// Per-sample forward + backprop features. One block per sample, 128 threads.
__global__ __launch_bounds__(128) void k_features(
    const float* __restrict__ X, const float* __restrict__ Z, const float* __restrict__ Xt,
    const float* __restrict__ W1, const float* __restrict__ b1,
    const float* __restrict__ W2, const float* __restrict__ b2,
    const float* __restrict__ W3, const float* __restrict__ W2T,
    float* __restrict__ XS, float* __restrict__ A1, float* __restrict__ A2,
    float* __restrict__ G1, float* __restrict__ G2)
{
  int s = blockIdx.x, h = threadIdx.x;
  const float* xin = (s < NX) ? X + s*DD : (s < NX+MZ ? Z + (s-NX)*DD : Xt + (s-NX-MZ)*DD);
  __shared__ float xs[DD], a1s[H], g2s[CC*H];
  float xv = xin[h];
  xs[h] = xv; XS[s*DD + h] = xv;
  __syncthreads();
  float acc = b1[h];
  #pragma unroll 4
  for (int d0 = 0; d0 < DD; ++d0) acc += xs[d0] * W1[d0*H + h];   // coalesced over h
  float a1 = tanhf(acc);
  a1s[h] = a1; A1[s*H + h] = a1;
  __syncthreads();
  acc = b2[h];
  #pragma unroll 4
  for (int d0 = 0; d0 < H; ++d0) acc += a1s[d0] * W2[d0*H + h];
  float a2 = tanhf(acc);
  A2[s*H + h] = a2;
  float t2 = 1.0f - a2*a2;
  #pragma unroll
  for (int c = 0; c < CC; ++c) {
    float g2 = W3[h*CC + c] * t2;
    g2s[c*H + h] = g2;
    G2[(s*CC + c)*H + h] = g2;
  }
  __syncthreads();
  float t1 = 1.0f - a1*a1;
  float accs[CC];
  #pragma unroll
  for (int c = 0; c < CC; ++c) accs[c] = 0.0f;
  for (int k = 0; k < H; ++k) {
    float w = W2T[k*H + h];        // coalesced over h
    #pragma unroll
    for (int c = 0; c < CC; ++c) accs[c] += w * g2s[c*H + k];   // broadcast
  }
  #pragma unroll
  for (int c = 0; c < CC; ++c) G1[(s*CC + c)*H + h] = t1 * accs[c];
}

// Class-independent base dot products: 1+x.x', 1+a1.a1', 1+a2.a2'
__global__ __launch_bounds__(256) void k_base(const float* __restrict__ XS,
    const float* __restrict__ A1, const float* __restrict__ A2, float* __restrict__ Base)
{
  int set = blockIdx.z;
  int colsN = (set == 0) ? NX : MZ;
  if ((int)blockIdx.x * 16 >= colsN) return;
  int rowOff = (set == 2) ? NX+MZ : NX;
  int colOff = (set == 0) ? 0 : NX;
  unsigned baseOff = (set == 0) ? BASE_ZX : (set == 1 ? BASE_ZZ : BASE_TZ);
  __shared__ float rx[16*132], r1[16*132], r2[16*132], cxs[16*132], c1s[16*132], c2s[16*132];
  int tid = threadIdx.x, m0 = blockIdx.y*16, n0 = blockIdx.x*16;
  for (int idx = tid; idx < 16*128; idx += 256) {
    int r = idx >> 7, hh = idx & 127;
    int sr = rowOff + m0 + r, sc = colOff + n0 + r;
    rx [r*132+hh] = XS[sr*DD+hh]; r1[r*132+hh] = A1[sr*H+hh]; r2[r*132+hh] = A2[sr*H+hh];
    cxs[r*132+hh] = XS[sc*DD+hh]; c1s[r*132+hh] = A1[sc*H+hh]; c2s[r*132+hh] = A2[sc*H+hh];
  }
  __syncthreads();
  int ty = tid >> 4, tx = tid & 15;
  const float4* pa = (const float4*)(rx  + ty*132);
  const float4* pb = (const float4*)(cxs + tx*132);
  const float4* pc = (const float4*)(r1  + ty*132);
  const float4* pd = (const float4*)(c1s + tx*132);
  const float4* pe = (const float4*)(r2  + ty*132);
  const float4* pf = (const float4*)(c2s + tx*132);
  float d0 = 0, d1 = 0, d2 = 0;
  #pragma unroll 8
  for (int q = 0; q < 32; ++q) {
    float4 a = pa[q], b = pb[q]; d0 += a.x*b.x + a.y*b.y + a.z*b.z + a.w*b.w;
    float4 c = pc[q], d = pd[q]; d1 += c.x*d.x + c.y*d.y + c.z*d.z + c.w*d.w;
    float4 e = pe[q], f = pf[q]; d2 += e.x*f.x + e.y*f.y + e.z*f.z + e.w*f.w;
  }
  int m = m0 + ty, n = n0 + tx;
  float* Bp = Base + baseOff;
  int area = 128 * colsN;
  Bp[0*area + m*colsN + n] = 1.0f + d0;
  Bp[1*area + m*colsN + n] = 1.0f + d1;
  Bp[2*area + m*colsN + n] = 1.0f + d2;
}

// Per-class NTK gram: K = SCALE*(B0*(g1.g1') + B1*(g2.g2') + B2)
// set==0 additionally folds LamU[c][m] += sum_n Kzx[m][n]*Y[n][c] via shuffles+atomics.
__global__ __launch_bounds__(256) void k_gram(const float* __restrict__ G1, const float* __restrict__ G2,
    const float* __restrict__ Base, const float* __restrict__ Y,
    float* __restrict__ Kzx, float* __restrict__ Kzz, float* __restrict__ Kxz,
    float* __restrict__ LamU)
{
  int z = blockIdx.z, set = z / CC, c = z % CC;
  int colsN = (set == 0) ? NX : MZ;
  if ((int)blockIdx.x * 16 >= colsN) return;
  int rowOff = (set == 2) ? NX+MZ : NX;
  int colOff = (set == 0) ? 0 : NX;
  unsigned baseOff = (set == 0) ? BASE_ZX : (set == 1 ? BASE_ZZ : BASE_TZ);
  float* outp = (set == 0) ? Kzx + c*MZ*NX : (set == 1 ? Kzz + c*MZ*MZ : Kxz + c*TN*MZ);
  __shared__ float g1r[16*132], g2r[16*132], g1c[16*132], g2c[16*132];
  int tid = threadIdx.x, m0 = blockIdx.y*16, n0 = blockIdx.x*16;
  for (int idx = tid; idx < 2048; idx += 256) {
    int r = idx >> 7, hh = idx & 127;
    int sr = rowOff + m0 + r, sc = colOff + n0 + r;
    g1r[r*132+hh] = G1[(sr*CC + c)*H + hh]; g2r[r*132+hh] = G2[(sr*CC + c)*H + hh];
    g1c[r*132+hh] = G1[(sc*CC + c)*H + hh]; g2c[r*132+hh] = G2[(sc*CC + c)*H + hh];
  }
  __syncthreads();
  int ty = tid >> 4, tx = tid & 15;
  const float4* p1 = (const float4*)(g1r + ty*132);
  const float4* p2 = (const float4*)(g1c + tx*132);
  const float4* p3 = (const float4*)(g2r + ty*132);
  const float4* p4 = (const float4*)(g2c + tx*132);
  float dg1 = 0, dg2 = 0;
  #pragma unroll 8
  for (int q = 0; q < 32; ++q) {
    float4 a = p1[q], b = p2[q]; dg1 += a.x*b.x + a.y*b.y + a.z*b.z + a.w*b.w;
    float4 e = p3[q], f = p4[q]; dg2 += e.x*f.x + e.y*f.y + e.z*f.z + e.w*f.w;
  }
  int m = m0 + ty, n = n0 + tx;
  const float* Bp = Base + baseOff;
  int area = 128 * colsN;
  float b0 = Bp[m*colsN + n], b1v = Bp[area + m*colsN + n], b2v = Bp[2*area + m*colsN + n];
  float val = SCALE * (b0*dg1 + b1v*dg2 + b2v);
  outp[m*colsN + n] = val;
  if (set == 0) {
    float lam = val * Y[n*CC + c] * INV_S2;
    lam += __shfl_xor(lam, 1, 64); lam += __shfl_xor(lam, 2, 64);
    lam += __shfl_xor(lam, 4, 64); lam += __shfl_xor(lam, 8, 64);
    if (tx == 0) atomicAdd(&LamU[c*MZ + m], lam);
  }
}

__device__ __forceinline__ float blockReduce128(float v, float* red, int h) {
  #pragma unroll
  for (int off = 32; off > 0; off >>= 1) v += __shfl_down(v, off, 64);
  if ((h & 63) == 0) red[h >> 6] = v;
  __syncthreads();
  float r = red[0] + red[1];
  __syncthreads();
  return r;
}

// Kxx_diag[c][t]; one block per test sample.
__global__ __launch_bounds__(128) void k_kxxd(const float* __restrict__ XS, const float* __restrict__ A1,
    const float* __restrict__ A2, const float* __restrict__ G1, const float* __restrict__ G2,
    float* __restrict__ Kxxd)
{
  int t = blockIdx.x, h = threadIdx.x, s = NX + MZ + t;
  __shared__ float red[2];
  float xv = XS[s*DD+h], a1v = A1[s*H+h], a2v = A2[s*H+h];
  float nx  = blockReduce128(xv*xv,  red, h);
  float na1 = blockReduce128(a1v*a1v, red, h);
  float na2 = blockReduce128(a2v*a2v, red, h);
  for (int c = 0; c < CC; ++c) {
    float g1 = G1[(s*CC+c)*H+h], g2 = G2[(s*CC+c)*H+h];
    float n1 = blockReduce128(g1*g1, red, h);
    float n2 = blockReduce128(g2*g2, red, h);
    if (h == 0) Kxxd[c*TN + t] = SCALE * ((1.0f+nx)*n1 + (1.0f+na1)*n2 + (1.0f+na2));
  }
}

// KzzB = Kzz + Kzx Kzx^T / sigma2 + 2*JIT*I ; Kzzj = Kzz + JIT*I
__global__ __launch_bounds__(256) void k_kzzb(const float* __restrict__ Kzx, const float* __restrict__ Kzz,
    float* __restrict__ Kzzj, float* __restrict__ KzzB)
{
  int c = blockIdx.z, m0 = blockIdx.y*16, k0 = blockIdx.x*16;
  int tid = threadIdx.x, ty = tid >> 4, tx = tid & 15;
  __shared__ float Am[16*17], Ak[16*17];
  const float* Kc = Kzx + c*MZ*NX;
  float acc = 0;
  for (int nc = 0; nc < NX; nc += 16) {
    Am[ty*17+tx] = Kc[(m0+ty)*NX + nc + tx];
    Ak[ty*17+tx] = Kc[(k0+ty)*NX + nc + tx];
    __syncthreads();
    #pragma unroll
    for (int p = 0; p < 16; ++p) acc += Am[ty*17+p] * Ak[tx*17+p];
    __syncthreads();
  }
  int m = m0+ty, k = k0+tx, idx = c*MZ*MZ + m*MZ + k;
  float kzz = Kzz[idx];
  float dia = (m == k) ? 1.0f : 0.0f;
  Kzzj[idx] = kzz + dia*JIT;
  KzzB[idx] = kzz + acc*INV_S2 + dia*2.0f*JIT;
}

// Blocked (rank-4) Cholesky (R3 form, ~10us) + folded ylam forward-subst.
// Emits Lc col-major with ZEROS at/above the diagonal (so k_solve's update
// needs no guards), invd = 1/diag, ylam (which==1).
__global__ __launch_bounds__(512) void k_chol(const float* __restrict__ Kzzj, const float* __restrict__ KzzB,
    float* __restrict__ Lc, float* __restrict__ invd,
    const float* __restrict__ LamU, float* __restrict__ ylam)
{
  int which = blockIdx.x & 1, c = blockIdx.x >> 1;
  const float* Ain = (which ? KzzB : Kzzj) + c*MZ*MZ;
  float* LcB = Lc + (size_t)(which*CC + c)*MZ*MZ;
  float* invB = invd + (which*CC + c)*MZ;
  __shared__ float As[MZ*MZ];    // col-major; input symmetric so straight copy is fine
  __shared__ float4 pan[MZ];     // scaled panel (separate object -> no alias with As)
  __shared__ float bs[MZ];       // running RHS residual for ylam
  __shared__ float ys[MZ];       // ylam solution
  int tid = threadIdx.x;
  int i = tid & 127, kh = tid >> 7;   // kh in 0..3
  {
    float4* d4 = (float4*)As; const float4* s4 = (const float4*)Ain;
    for (int idx = tid; idx < MZ*MZ/4; idx += 512) d4[idx] = s4[idx];
  }
  if (tid < MZ) bs[tid] = which ? LamU[c*MZ + tid] : 0.0f;
  __syncthreads();
  for (int j = 0; j < MZ; j += 4) {
    float r0 = As[(j+0)*MZ + i], r1 = As[(j+1)*MZ + i], r2 = As[(j+2)*MZ + i], r3 = As[(j+3)*MZ + i];
    float a00 = As[j*MZ+j];
    float a10 = As[j*MZ+j+1], a20 = As[j*MZ+j+2], a30 = As[j*MZ+j+3];
    float a11 = As[(j+1)*MZ+j+1], a21 = As[(j+1)*MZ+j+2], a31 = As[(j+1)*MZ+j+3];
    float a22 = As[(j+2)*MZ+j+2], a32 = As[(j+2)*MZ+j+3];
    float a33 = As[(j+3)*MZ+j+3];
    float bj0 = bs[j], bj1 = bs[j+1], bj2 = bs[j+2], bj3 = bs[j+3];
    float id0 = rsqrtf(a00);
    float l10 = a10*id0, l20 = a20*id0, l30 = a30*id0;
    float id1 = rsqrtf(a11 - l10*l10);
    float l21 = (a21 - l20*l10)*id1, l31 = (a31 - l30*l10)*id1;
    float id2 = rsqrtf(a22 - l20*l20 - l21*l21);
    float l32 = (a32 - l30*l20 - l31*l21)*id2;
    float id3 = rsqrtf(a33 - l30*l30 - l31*l31 - l32*l32);
    float c0 = r0*id0;
    float c1 = (r1 - c0*l10)*id1;
    float c2 = (r2 - c0*l20 - c1*l21)*id2;
    float c3 = (r3 - c0*l30 - c1*l31 - c2*l32)*id3;
    // ylam chain (identical recurrence, one extra "column")
    float y0 = bj0*id0;
    float y1 = (bj1 - l10*y0)*id1;
    float y2 = (bj2 - l20*y0 - l21*y1)*id2;
    float y3 = (bj3 - l30*y0 - l31*y1 - l32*y2)*id3;
    if (kh == 0) {
      pan[i] = make_float4(c0, c1, c2, c3);
      // strictly-lower Lc (zero at/above diag) -> k_solve updates unguarded
      LcB[(j+0)*MZ + i] = (i > j+0) ? c0 : 0.0f;
      LcB[(j+1)*MZ + i] = (i > j+1) ? c1 : 0.0f;
      LcB[(j+2)*MZ + i] = (i > j+2) ? c2 : 0.0f;
      LcB[(j+3)*MZ + i] = (i > j+3) ? c3 : 0.0f;
      if (i == j) {
        invB[j] = id0; invB[j+1] = id1; invB[j+2] = id2; invB[j+3] = id3;
        ys[j] = y0; ys[j+1] = y1; ys[j+2] = y2; ys[j+3] = y3;
      }
      if (i >= j+4) bs[i] -= c0*y0 + c1*y1 + c2*y2 + c3*y3;   // thread-local c = L[i][j..j+3]
    }
    __syncthreads();   // pan visible; bs updates done
    for (int kb = j + 4 + kh; kb < MZ; kb += 32) {
      float4 pv[8]; float av[8];
      #pragma unroll
      for (int q = 0; q < 8; ++q) {
        int k = kb + 4*q;
        if (k < MZ) { pv[q] = pan[k]; av[q] = As[k*MZ + i]; }
      }
      #pragma unroll
      for (int q = 0; q < 8; ++q) {
        int k = kb + 4*q;
        if (k < MZ) As[k*MZ + i] = av[q] - (c0*pv[q].x + c1*pv[q].y + c2*pv[q].z + c3*pv[q].w);
      }
    }
    __syncthreads();   // trailing writes visible before next step's reads
  }
  if (which && tid < MZ) ylam[c*MZ + tid] = ys[tid];
}

// ----------------------------------------------------------------------------
// Forward substitution L W = Kzxt, wave-distributed columns. Lane l holds rows
// (2l, 2l+1) of 4 columns as 8 NAMED float2 components (no arrays). Step j
// (fully unrolled, compile-time): ds_read_b64 of L column j (zeroed at/above
// diag -> unguarded FMA update), y = readlane(b*inv, j>>1) (immediate lane),
// owner overwrites its residual with y. grid 80 = (c, which, quarter);
// 512 thr = 8 waves x 4 columns. ssq/fmean via shfl_xor reduce.
// ----------------------------------------------------------------------------
__device__ __forceinline__ float rdlane(float v, int lane) {
  return __int_as_float(__builtin_amdgcn_readlane(__float_as_int(v), lane));
}

__global__ __launch_bounds__(512) void k_solve(const float* __restrict__ Lc,
    const float* __restrict__ invd, const float* __restrict__ ylam,
    const float* __restrict__ Kxz, float* __restrict__ ssq, float* __restrict__ fmean)
{
  int quarter = blockIdx.x & 3;
  int which   = (blockIdx.x >> 2) & 1;
  int c       = blockIdx.x >> 3;
  const float2* LcB2 = (const float2*)(Lc + (size_t)(which*CC + c)*MZ*MZ);
  const float2* invB2 = (const float2*)(invd + (which*CC + c)*MZ);
  const float2* ylB2  = (const float2*)(ylam + c*MZ);
  int tid = threadIdx.x, l = tid & 63, wv = tid >> 6;
  __shared__ float2 Ls[MZ*64];   // 64 KB: Ls[j*64 + l] = L[2l..2l+1][j]
  #pragma unroll
  for (int r = 0; r < 16; ++r) Ls[tid + 512*r] = LcB2[tid + 512*r];
  float2 iv = invB2[l];
  float2 yl = ylB2[l];
  int col0 = quarter*32 + wv*4;
  const float* K0 = Kxz + (size_t)c*TN*MZ;
  float2 b0 = *(const float2*)(K0 + (size_t)(col0+0)*MZ + 2*l);
  float2 b1 = *(const float2*)(K0 + (size_t)(col0+1)*MZ + 2*l);
  float2 b2 = *(const float2*)(K0 + (size_t)(col0+2)*MZ + 2*l);
  float2 b3 = *(const float2*)(K0 + (size_t)(col0+3)*MZ + 2*l);
  __syncthreads();
  #pragma unroll
  for (int j = 0; j < MZ; ++j) {
    const int owner = j >> 1;
    float2 Lj = Ls[j*64 + l];
    float y0, y1, y2, y3;
    if ((j & 1) == 0) {
      y0 = rdlane(b0.x * iv.x, owner);
      y1 = rdlane(b1.x * iv.x, owner);
      y2 = rdlane(b2.x * iv.x, owner);
      y3 = rdlane(b3.x * iv.x, owner);
    } else {
      y0 = rdlane(b0.y * iv.y, owner);
      y1 = rdlane(b1.y * iv.y, owner);
      y2 = rdlane(b2.y * iv.y, owner);
      y3 = rdlane(b3.y * iv.y, owner);
    }
    // unguarded: Lj components are 0 at/above the diagonal
    b0.x -= Lj.x * y0; b0.y -= Lj.y * y0;
    b1.x -= Lj.x * y1; b1.y -= Lj.y * y1;
    b2.x -= Lj.x * y2; b2.y -= Lj.y * y2;
    b3.x -= Lj.x * y3; b3.y -= Lj.y * y3;
    if (l == owner) {
      if ((j & 1) == 0) { b0.x = y0; b1.x = y1; b2.x = y2; b3.x = y3; }
      else              { b0.y = y0; b1.y = y1; b2.y = y2; b3.y = y3; }
    }
  }
  float sq0 = b0.x*b0.x + b0.y*b0.y, fm0 = b0.x*yl.x + b0.y*yl.y;
  float sq1 = b1.x*b1.x + b1.y*b1.y, fm1 = b1.x*yl.x + b1.y*yl.y;
  float sq2 = b2.x*b2.x + b2.y*b2.y, fm2 = b2.x*yl.x + b2.y*yl.y;
  float sq3 = b3.x*b3.x + b3.y*b3.y, fm3 = b3.x*yl.x + b3.y*yl.y;
  #pragma unroll
  for (int off = 32; off > 0; off >>= 1) {
    sq0 += __shfl_xor(sq0, off, 64); fm0 += __shfl_xor(fm0, off, 64);
    sq1 += __shfl_xor(sq1, off, 64); fm1 += __shfl_xor(fm1, off, 64);
    sq2 += __shfl_xor(sq2, off, 64); fm2 += __shfl_xor(fm2, off, 64);
    sq3 += __shfl_xor(sq3, off, 64); fm3 += __shfl_xor(fm3, off, 64);
  }
  if (l == 0) {
    float* sp = ssq + (size_t)(which*CC + c)*TN + col0;
    sp[0] = sq0; sp[1] = sq1; sp[2] = sq2; sp[3] = sq3;
    if (which) {
      float* fp = fmean + (size_t)c*TN + col0;
      fp[0] = fm0; fp[1] = fm1; fp[2] = fm2; fp[3] = fm3;
    }
  }
}

// out[0][t][c] = f_mean ; out[1][t][c] = f_var.T = Kxx - sum(Am^2) + sum(Ab^2)
__global__ __launch_bounds__(256) void k_final(const float* __restrict__ fmean, const float* __restrict__ Kxxd,
    const float* __restrict__ ssq, float* __restrict__ out)
{
  int idx = blockIdx.x*256 + threadIdx.x;
  if (idx >= TN*CC) return;
  int t = idx / CC, c = idx % CC;
  out[idx] = fmean[c*TN + t];
  out[TN*CC + idx] = Kxxd[c*TN + t] - ssq[c*TN + t] + ssq[CC*TN + c*TN + t];
}

extern "C" void kernel_launch(void* const* d_in, const int* in_sizes, int n_in,
                              void* d_out, int out_size, void* d_ws, size_t ws_size,
                              hipStream_t stream) {
  (void)in_sizes; (void)n_in; (void)out_size; (void)ws_size;
  const float* X  = (const float*)d_in[0];
  const float* Y  = (const float*)d_in[1];
  const float* Z  = (const float*)d_in[2];
  const float* Xt = (const float*)d_in[3];
  const float* W1 = (const float*)d_in[4];
  const float* b1 = (const float*)d_in[5];
  const float* W2 = (const float*)d_in[6];
  const float* b2 = (const float*)d_in[7];
  const float* W3 = (const float*)d_in[8];
  float* ws  = (float*)d_ws;
  float* out = (float*)d_out;

  float* XS   = ws + OFF_XS;
  float* A1   = ws + OFF_A1;
  float* A2   = ws + OFF_A2;
  float* G1   = ws + OFF_G1;
  float* G2   = ws + OFF_G2;
  float* W2T  = ws + OFF_W2T;
  float* Base = ws + OFF_BASE;
  float* Kzx  = ws + OFF_KZX;
  float* Kzz  = ws + OFF_KZZ;
  float* Kxz  = ws + OFF_KXZ;
  float* Kxxd = ws + OFF_KXXD;
  float* Kzzj = ws + OFF_KZZJ;
  float* KzzB = ws + OFF_KZZB;
  float* LamU = ws + OFF_LAMU;
  float* Lc   = ws + OFF_LC;
  float* invd = ws + OFF_INVD;
  float* ylam = ws + OFF_YLAM;
  float* ssq  = ws + OFF_SSQ;
  float* fmean= ws + OFF_FMEAN;

  k_w2t<<<128, 128, 0, stream>>>(W2, W2T, LamU);
  k_features<<<S_TOT, 128, 0, stream>>>(X, Z, Xt, W1, b1, W2, b2, W3, W2T, XS, A1, A2, G1, G2);
  k_base<<<dim3(16, 8, 3), 256, 0, stream>>>(XS, A1, A2, Base);
  k_gram<<<dim3(16, 8, 3*CC), 256, 0, stream>>>(G1, G2, Base, Y, Kzx, Kzz, Kxz, LamU);
  k_kxxd<<<TN, 128, 0, stream>>>(XS, A1, A2, G1, G2, Kxxd);
  k_kzzb<<<dim3(8, 8, CC), 256, 0, stream>>>(Kzx, Kzz, Kzzj, KzzB);
  k_chol<<<2*CC, 512, 0, stream>>>(Kzzj, KzzB, Lc, invd, LamU, ylam);
  k_solve<<<8*CC, 512, 0, stream>>>(Lc, invd, ylam, Kxz, ssq, fmean);
  k_final<<<(TN*CC + 255)/256, 256, 0, stream>>>(fmean, Kxxd, ssq, out);
}

// Round 12
// 137.084 us; speedup vs baseline: 1.1712x; 1.1712x over previous
//
#include <hip/hip_runtime.h>

// NTK-SVGP forward: D=H=128, C=10, N=256, M=128, T=128, sigma2=1, delta=1
#define H 128
#define DD 128
#define CC 10
#define NX 256
#define MZ 128
#define TN 128
#define S_TOT 512   // samples: X[0..255], Z[256..383], X_test[384..511]
#define SCALE (1.0f/256.0f)   // 1/(delta*N)
#define JIT 1e-3f
#define INV_S2 1.0f

// ---------------- ws layout (float offsets) ----------------
#define OFF_XS    0u
#define OFF_A1    (OFF_XS   + S_TOT*DD)
#define OFF_A2    (OFF_A1   + S_TOT*H)
#define OFF_G1    (OFF_A2   + S_TOT*H)
#define OFF_G2    (OFF_G1   + S_TOT*CC*H)
#define OFF_W2T   (OFF_G2   + S_TOT*CC*H)
#define OFF_BASE  (OFF_W2T  + H*H)
#define BASE_ZX   0u
#define BASE_ZZ   (3u*MZ*NX)
#define BASE_TZ   (3u*MZ*NX + 3u*MZ*MZ)
#define OFF_KZX   (OFF_BASE + 3u*MZ*NX + 3u*MZ*MZ + 3u*TN*MZ)
#define OFF_KZZ   (OFF_KZX  + CC*MZ*NX)
#define OFF_KXZ   (OFF_KZZ  + CC*MZ*MZ)
#define OFF_KZZJ  (OFF_KXZ  + CC*TN*MZ)
#define OFF_KZZB  (OFF_KZZJ + CC*MZ*MZ)
#define OFF_LAMU  (OFF_KZZB + CC*MZ*MZ)
#define OFF_LC    (OFF_LAMU + CC*MZ)
#define OFF_INVD  (OFF_LC   + 2u*CC*MZ*MZ)
#define OFF_YLAM  (OFF_INVD + 2u*CC*MZ)

__global__ __launch_bounds__(128) void k_w2t(const float* __restrict__ W2, float* __restrict__ W2T,
                                             float* __restrict__ LamU) {
  int k = blockIdx.x, h = threadIdx.x;
  W2T[k*H + h] = W2[h*H + k];
  if (k < CC) LamU[k*MZ + h] = 0.0f;   // zero for k_gram's atomic accumulation
}

// Per-sample forward + backprop features. One block per sample, 128 threads.
// Test-sample blocks (s >= NX+MZ) also emit Kxx_diag straight into out's
// f_var half: out[TN*CC + t*CC + c] = Kxxd (k_solve atomicAdds ±ssq on top).
__global__ __launch_bounds__(128) void k_features(
    const float* __restrict__ X, const float* __restrict__ Z, const float* __restrict__ Xt,
    const float* __restrict__ W1, const float* __restrict__ b1,
    const float* __restrict__ W2, const float* __restrict__ b2,
    const float* __restrict__ W3, const float* __restrict__ W2T,
    float* __restrict__ XS, float* __restrict__ A1, float* __restrict__ A2,
    float* __restrict__ G1, float* __restrict__ G2, float* __restrict__ out)
{
  int s = blockIdx.x, h = threadIdx.x;
  const float* xin = (s < NX) ? X + s*DD : (s < NX+MZ ? Z + (s-NX)*DD : Xt + (s-NX-MZ)*DD);
  __shared__ float xs[DD], a1s[H], g2s[CC*H];
  __shared__ float red[2];
  float xv = xin[h];
  xs[h] = xv; XS[s*DD + h] = xv;
  __syncthreads();
  float acc = b1[h];
  #pragma unroll 4
  for (int d0 = 0; d0 < DD; ++d0) acc += xs[d0] * W1[d0*H + h];   // coalesced over h
  float a1 = tanhf(acc);
  a1s[h] = a1; A1[s*H + h] = a1;
  __syncthreads();
  acc = b2[h];
  #pragma unroll 4
  for (int d0 = 0; d0 < H; ++d0) acc += a1s[d0] * W2[d0*H + h];
  float a2 = tanhf(acc);
  A2[s*H + h] = a2;
  float t2 = 1.0f - a2*a2;
  #pragma unroll
  for (int c = 0; c < CC; ++c) {
    float g2 = W3[h*CC + c] * t2;
    g2s[c*H + h] = g2;
    G2[(s*CC + c)*H + h] = g2;
  }
  __syncthreads();
  float t1 = 1.0f - a1*a1;
  float accs[CC];
  #pragma unroll
  for (int c = 0; c < CC; ++c) accs[c] = 0.0f;
  for (int k = 0; k < H; ++k) {
    float w = W2T[k*H + h];        // coalesced over h
    #pragma unroll
    for (int c = 0; c < CC; ++c) accs[c] += w * g2s[c*H + k];   // broadcast
  }
  #pragma unroll
  for (int c = 0; c < CC; ++c) G1[(s*CC + c)*H + h] = t1 * accs[c];
  // ---- fused Kxx_diag for test samples (block-uniform branch) ----
  if (s >= NX + MZ) {
    int t = s - NX - MZ;
    // local reduce helper inline (wave shuffle + 2-elem LDS combine)
    float v, nx, na1, na2;
    v = xv*xv;
    #pragma unroll
    for (int off = 32; off > 0; off >>= 1) v += __shfl_down(v, off, 64);
    if ((h & 63) == 0) red[h >> 6] = v;
    __syncthreads(); nx = red[0] + red[1]; __syncthreads();
    v = a1*a1;
    #pragma unroll
    for (int off = 32; off > 0; off >>= 1) v += __shfl_down(v, off, 64);
    if ((h & 63) == 0) red[h >> 6] = v;
    __syncthreads(); na1 = red[0] + red[1]; __syncthreads();
    v = a2*a2;
    #pragma unroll
    for (int off = 32; off > 0; off >>= 1) v += __shfl_down(v, off, 64);
    if ((h & 63) == 0) red[h >> 6] = v;
    __syncthreads(); na2 = red[0] + red[1]; __syncthreads();
    float base1 = 1.0f + nx, base2 = 1.0f + na1, base3 = 1.0f + na2;
    #pragma unroll
    for (int c = 0; c < CC; ++c) {
      float g1v = t1 * accs[c];
      float g2v = g2s[c*H + h];
      float n1, n2;
      v = g1v*g1v;
      #pragma unroll
      for (int off = 32; off > 0; off >>= 1) v += __shfl_down(v, off, 64);
      if ((h & 63) == 0) red[h >> 6] = v;
      __syncthreads(); n1 = red[0] + red[1]; __syncthreads();
      v = g2v*g2v;
      #pragma unroll
      for (int off = 32; off > 0; off >>= 1) v += __shfl_down(v, off, 64);
      if ((h & 63) == 0) red[h >> 6] = v;
      __syncthreads(); n2 = red[0] + red[1]; __syncthreads();
      if (h == 0) out[TN*CC + t*CC + c] = SCALE * (base1*n1 + base2*n2 + base3);
    }
  }
}

// Class-independent base dot products: 1+x.x', 1+a1.a1', 1+a2.a2'
__global__ __launch_bounds__(256) void k_base(const float* __restrict__ XS,
    const float* __restrict__ A1, const float* __restrict__ A2, float* __restrict__ Base)
{
  int set = blockIdx.z;
  int colsN = (set == 0) ? NX : MZ;
  if ((int)blockIdx.x * 16 >= colsN) return;
  int rowOff = (set == 2) ? NX+MZ : NX;
  int colOff = (set == 0) ? 0 : NX;
  unsigned baseOff = (set == 0) ? BASE_ZX : (set == 1 ? BASE_ZZ : BASE_TZ);
  __shared__ float rx[16*132], r1[16*132], r2[16*132], cxs[16*132], c1s[16*132], c2s[16*132];
  int tid = threadIdx.x, m0 = blockIdx.y*16, n0 = blockIdx.x*16;
  for (int idx = tid; idx < 16*128; idx += 256) {
    int r = idx >> 7, hh = idx & 127;
    int sr = rowOff + m0 + r, sc = colOff + n0 + r;
    rx [r*132+hh] = XS[sr*DD+hh]; r1[r*132+hh] = A1[sr*H+hh]; r2[r*132+hh] = A2[sr*H+hh];
    cxs[r*132+hh] = XS[sc*DD+hh]; c1s[r*132+hh] = A1[sc*H+hh]; c2s[r*132+hh] = A2[sc*H+hh];
  }
  __syncthreads();
  int ty = tid >> 4, tx = tid & 15;
  const float4* pa = (const float4*)(rx  + ty*132);
  const float4* pb = (const float4*)(cxs + tx*132);
  const float4* pc = (const float4*)(r1  + ty*132);
  const float4* pd = (const float4*)(c1s + tx*132);
  const float4* pe = (const float4*)(r2  + ty*132);
  const float4* pf = (const float4*)(c2s + tx*132);
  float d0 = 0, d1 = 0, d2 = 0;
  #pragma unroll 8
  for (int q = 0; q < 32; ++q) {
    float4 a = pa[q], b = pb[q]; d0 += a.x*b.x + a.y*b.y + a.z*b.z + a.w*b.w;
    float4 c = pc[q], d = pd[q]; d1 += c.x*d.x + c.y*d.y + c.z*d.z + c.w*d.w;
    float4 e = pe[q], f = pf[q]; d2 += e.x*f.x + e.y*f.y + e.z*f.z + e.w*f.w;
  }
  int m = m0 + ty, n = n0 + tx;
  float* Bp = Base + baseOff;
  int area = 128 * colsN;
  Bp[0*area + m*colsN + n] = 1.0f + d0;
  Bp[1*area + m*colsN + n] = 1.0f + d1;
  Bp[2*area + m*colsN + n] = 1.0f + d2;
}

// Per-class NTK gram: K = SCALE*(B0*(g1.g1') + B1*(g2.g2') + B2)
// set==0 additionally folds LamU[c][m] += sum_n Kzx[m][n]*Y[n][c] via shuffles+atomics.
__global__ __launch_bounds__(256) void k_gram(const float* __restrict__ G1, const float* __restrict__ G2,
    const float* __restrict__ Base, const float* __restrict__ Y,
    float* __restrict__ Kzx, float* __restrict__ Kzz, float* __restrict__ Kxz,
    float* __restrict__ LamU)
{
  int z = blockIdx.z, set = z / CC, c = z % CC;
  int colsN = (set == 0) ? NX : MZ;
  if ((int)blockIdx.x * 16 >= colsN) return;
  int rowOff = (set == 2) ? NX+MZ : NX;
  int colOff = (set == 0) ? 0 : NX;
  unsigned baseOff = (set == 0) ? BASE_ZX : (set == 1 ? BASE_ZZ : BASE_TZ);
  float* outp = (set == 0) ? Kzx + c*MZ*NX : (set == 1 ? Kzz + c*MZ*MZ : Kxz + c*TN*MZ);
  __shared__ float g1r[16*132], g2r[16*132], g1c[16*132], g2c[16*132];
  int tid = threadIdx.x, m0 = blockIdx.y*16, n0 = blockIdx.x*16;
  for (int idx = tid; idx < 2048; idx += 256) {
    int r = idx >> 7, hh = idx & 127;
    int sr = rowOff + m0 + r, sc = colOff + n0 + r;
    g1r[r*132+hh] = G1[(sr*CC + c)*H + hh]; g2r[r*132+hh] = G2[(sr*CC + c)*H + hh];
    g1c[r*132+hh] = G1[(sc*CC + c)*H + hh]; g2c[r*132+hh] = G2[(sc*CC + c)*H + hh];
  }
  __syncthreads();
  int ty = tid >> 4, tx = tid & 15;
  const float4* p1 = (const float4*)(g1r + ty*132);
  const float4* p2 = (const float4*)(g1c + tx*132);
  const float4* p3 = (const float4*)(g2r + ty*132);
  const float4* p4 = (const float4*)(g2c + tx*132);
  float dg1 = 0, dg2 = 0;
  #pragma unroll 8
  for (int q = 0; q < 32; ++q) {
    float4 a = p1[q], b = p2[q]; dg1 += a.x*b.x + a.y*b.y + a.z*b.z + a.w*b.w;
    float4 e = p3[q], f = p4[q]; dg2 += e.x*f.x + e.y*f.y + e.z*f.z + e.w*f.w;
  }
  int m = m0 + ty, n = n0 + tx;
  const float* Bp = Base + baseOff;
  int area = 128 * colsN;
  float b0 = Bp[m*colsN + n], b1v = Bp[area + m*colsN + n], b2v = Bp[2*area + m*colsN + n];
  float val = SCALE * (b0*dg1 + b1v*dg2 + b2v);
  outp[m*colsN + n] = val;
  if (set == 0) {
    float lam = val * Y[n*CC + c] * INV_S2;
    lam += __shfl_xor(lam, 1, 64); lam += __shfl_xor(lam, 2, 64);
    lam += __shfl_xor(lam, 4, 64); lam += __shfl_xor(lam, 8, 64);
    if (tx == 0) atomicAdd(&LamU[c*MZ + m], lam);
  }
}

// KzzB = Kzz + Kzx Kzx^T / sigma2 + 2*JIT*I ; Kzzj = Kzz + JIT*I
__global__ __launch_bounds__(256) void k_kzzb(const float* __restrict__ Kzx, const float* __restrict__ Kzz,
    float* __restrict__ Kzzj, float* __restrict__ KzzB)
{
  int c = blockIdx.z, m0 = blockIdx.y*16, k0 = blockIdx.x*16;
  int tid = threadIdx.x, ty = tid >> 4, tx = tid & 15;
  __shared__ float Am[16*17], Ak[16*17];
  const float* Kc = Kzx + c*MZ*NX;
  float acc = 0;
  for (int nc = 0; nc < NX; nc += 16) {
    Am[ty*17+tx] = Kc[(m0+ty)*NX + nc + tx];
    Ak[ty*17+tx] = Kc[(k0+ty)*NX + nc + tx];
    __syncthreads();
    #pragma unroll
    for (int p = 0; p < 16; ++p) acc += Am[ty*17+p] * Ak[tx*17+p];
    __syncthreads();
  }
  int m = m0+ty, k = k0+tx, idx = c*MZ*MZ + m*MZ + k;
  float kzz = Kzz[idx];
  float dia = (m == k) ? 1.0f : 0.0f;
  Kzzj[idx] = kzz + dia*JIT;
  KzzB[idx] = kzz + acc*INV_S2 + dia*2.0f*JIT;
}

// Blocked (rank-4) Cholesky + folded ylam forward-subst, float4-vectorized
// TRIANGULAR trailing update (R10's As4 rg/kp scheme: ~8x fewer LDS instrs
// than the scalar full-rectangle form that measured 55us in R11).
// Emits Lc col-major with ZEROS at/above the diagonal, invd, ylam (which==1).
__global__ __launch_bounds__(512) void k_chol(const float* __restrict__ Kzzj, const float* __restrict__ KzzB,
    float* __restrict__ Lc, float* __restrict__ invd,
    const float* __restrict__ LamU, float* __restrict__ ylam)
{
  int which = blockIdx.x & 1, c = blockIdx.x >> 1;
  const float* Ain = (which ? KzzB : Kzzj) + c*MZ*MZ;
  float* LcB = Lc + (size_t)(which*CC + c)*MZ*MZ;
  float* invB = invd + (which*CC + c)*MZ;
  __shared__ float As[MZ*MZ];    // col-major; input symmetric so straight copy is fine
  __shared__ float4 pan[MZ];     // scaled panel (separate object -> no alias with As)
  __shared__ float bs[MZ];       // running RHS residual for ylam
  __shared__ float ys[MZ];       // ylam solution
  int tid = threadIdx.x;
  int rg = tid & 31, kp = tid >> 5;   // update-phase decomposition
  float4* As4 = (float4*)As;
  {
    float4* d4 = (float4*)As; const float4* s4 = (const float4*)Ain;
    #pragma unroll
    for (int r = 0; r < 8; ++r) d4[tid + 512*r] = s4[tid + 512*r];
  }
  if (tid < MZ) bs[tid] = which ? LamU[c*MZ + tid] : 0.0f;
  __syncthreads();
  for (int jb = 0; jb < 32; ++jb) {
    int j = jb*4;
    if (tid < MZ) {
      int i = tid;
      float r0 = As[(j+0)*MZ + i], r1 = As[(j+1)*MZ + i], r2 = As[(j+2)*MZ + i], r3 = As[(j+3)*MZ + i];
      float a00 = As[j*MZ+j];
      float a10 = As[j*MZ+j+1], a20 = As[j*MZ+j+2], a30 = As[j*MZ+j+3];
      float a11 = As[(j+1)*MZ+j+1], a21 = As[(j+1)*MZ+j+2], a31 = As[(j+1)*MZ+j+3];
      float a22 = As[(j+2)*MZ+j+2], a32 = As[(j+2)*MZ+j+3];
      float a33 = As[(j+3)*MZ+j+3];
      float bj0 = bs[j], bj1 = bs[j+1], bj2 = bs[j+2], bj3 = bs[j+3];
      float id0 = rsqrtf(a00);
      float l10 = a10*id0, l20 = a20*id0, l30 = a30*id0;
      float id1 = rsqrtf(a11 - l10*l10);
      float l21 = (a21 - l20*l10)*id1, l31 = (a31 - l30*l10)*id1;
      float id2 = rsqrtf(a22 - l20*l20 - l21*l21);
      float l32 = (a32 - l30*l20 - l31*l21)*id2;
      float id3 = rsqrtf(a33 - l30*l30 - l31*l31 - l32*l32);
      float c0 = r0*id0;
      float c1 = (r1 - c0*l10)*id1;
      float c2 = (r2 - c0*l20 - c1*l21)*id2;
      float c3 = (r3 - c0*l30 - c1*l31 - c2*l32)*id3;
      float y0 = bj0*id0;
      float y1 = (bj1 - l10*y0)*id1;
      float y2 = (bj2 - l20*y0 - l21*y1)*id2;
      float y3 = (bj3 - l30*y0 - l31*y1 - l32*y2)*id3;
      pan[i] = make_float4(c0, c1, c2, c3);
      // strictly-lower Lc (zero at/above diag) -> k_solve updates unguarded
      LcB[(j+0)*MZ + i] = (i > j+0) ? c0 : 0.0f;
      LcB[(j+1)*MZ + i] = (i > j+1) ? c1 : 0.0f;
      LcB[(j+2)*MZ + i] = (i > j+2) ? c2 : 0.0f;
      LcB[(j+3)*MZ + i] = (i > j+3) ? c3 : 0.0f;
      if (i == j) {
        invB[j] = id0; invB[j+1] = id1; invB[j+2] = id2; invB[j+3] = id3;
        ys[j] = y0; ys[j+1] = y1; ys[j+2] = y2; ys[j+3] = y3;
      }
      if (i >= j+4) bs[i] -= c0*y0 + c1*y1 + c2*y2 + c3*y3;   // c = L[i][j..j+3]
    }
    __syncthreads();   // pan visible; bs updates done
    // float4 triangular trailing update: thread (rg,kp) owns rows 4rg..4rg+3,
    // columns k ≡ kp (mod 16), k in [j+4, 4rg+3] (chunks at/below diagonal).
    float4 p0 = pan[4*rg+0], p1 = pan[4*rg+1], p2 = pan[4*rg+2], p3 = pan[4*rg+3];
    int kstart = (j + 4) + ((kp - (j + 4)) & 15);
    int kend = 4*rg + 3;
    for (int k = kstart; k <= kend; k += 16) {
      float4 ck = pan[k];
      float4 a4 = As4[k*32 + rg];
      a4.x -= p0.x*ck.x + p0.y*ck.y + p0.z*ck.z + p0.w*ck.w;
      a4.y -= p1.x*ck.x + p1.y*ck.y + p1.z*ck.z + p1.w*ck.w;
      a4.z -= p2.x*ck.x + p2.y*ck.y + p2.z*ck.z + p2.w*ck.w;
      a4.w -= p3.x*ck.x + p3.y*ck.y + p3.z*ck.z + p3.w*ck.w;
      As4[k*32 + rg] = a4;
    }
    __syncthreads();   // trailing writes visible before next panel's reads
  }
  if (which && tid < MZ) ylam[c*MZ + tid] = ys[tid];
}

// ----------------------------------------------------------------------------
// Forward substitution L W = Kzxt, wave-distributed columns (R11 form, fast).
// Now ALSO finalizes the output: lane 0 atomicAdds ±sum(W^2) onto the Kxxd
// base that k_features wrote into out's f_var half, and (which==1) writes
// f_mean directly. k_final eliminated.
// ----------------------------------------------------------------------------
__device__ __forceinline__ float rdlane(float v, int lane) {
  return __int_as_float(__builtin_amdgcn_readlane(__float_as_int(v), lane));
}

__global__ __launch_bounds__(512) void k_solve(const float* __restrict__ Lc,
    const float* __restrict__ invd, const float* __restrict__ ylam,
    const float* __restrict__ Kxz, float* __restrict__ out)
{
  int quarter = blockIdx.x & 3;
  int which   = (blockIdx.x >> 2) & 1;
  int c       = blockIdx.x >> 3;
  const float2* LcB2 = (const float2*)(Lc + (size_t)(which*CC + c)*MZ*MZ);
  const float2* invB2 = (const float2*)(invd + (which*CC + c)*MZ);
  const float2* ylB2  = (const float2*)(ylam + c*MZ);
  int tid = threadIdx.x, l = tid & 63, wv = tid >> 6;
  __shared__ float2 Ls[MZ*64];   // 64 KB: Ls[j*64 + l] = L[2l..2l+1][j]
  #pragma unroll
  for (int r = 0; r < 16; ++r) Ls[tid + 512*r] = LcB2[tid + 512*r];
  float2 iv = invB2[l];
  float2 yl = ylB2[l];
  int col0 = quarter*32 + wv*4;
  const float* K0 = Kxz + (size_t)c*TN*MZ;
  float2 b0 = *(const float2*)(K0 + (size_t)(col0+0)*MZ + 2*l);
  float2 b1 = *(const float2*)(K0 + (size_t)(col0+1)*MZ + 2*l);
  float2 b2 = *(const float2*)(K0 + (size_t)(col0+2)*MZ + 2*l);
  float2 b3 = *(const float2*)(K0 + (size_t)(col0+3)*MZ + 2*l);
  __syncthreads();
  #pragma unroll
  for (int j = 0; j < MZ; ++j) {
    const int owner = j >> 1;
    float2 Lj = Ls[j*64 + l];
    float y0, y1, y2, y3;
    if ((j & 1) == 0) {
      y0 = rdlane(b0.x * iv.x, owner);
      y1 = rdlane(b1.x * iv.x, owner);
      y2 = rdlane(b2.x * iv.x, owner);
      y3 = rdlane(b3.x * iv.x, owner);
    } else {
      y0 = rdlane(b0.y * iv.y, owner);
      y1 = rdlane(b1.y * iv.y, owner);
      y2 = rdlane(b2.y * iv.y, owner);
      y3 = rdlane(b3.y * iv.y, owner);
    }
    // unguarded: Lj components are 0 at/above the diagonal
    b0.x -= Lj.x * y0; b0.y -= Lj.y * y0;
    b1.x -= Lj.x * y1; b1.y -= Lj.y * y1;
    b2.x -= Lj.x * y2; b2.y -= Lj.y * y2;
    b3.x -= Lj.x * y3; b3.y -= Lj.y * y3;
    if (l == owner) {
      if ((j & 1) == 0) { b0.x = y0; b1.x = y1; b2.x = y2; b3.x = y3; }
      else              { b0.y = y0; b1.y = y1; b2.y = y2; b3.y = y3; }
    }
  }
  float sq0 = b0.x*b0.x + b0.y*b0.y, fm0 = b0.x*yl.x + b0.y*yl.y;
  float sq1 = b1.x*b1.x + b1.y*b1.y, fm1 = b1.x*yl.x + b1.y*yl.y;
  float sq2 = b2.x*b2.x + b2.y*b2.y, fm2 = b2.x*yl.x + b2.y*yl.y;
  float sq3 = b3.x*b3.x + b3.y*b3.y, fm3 = b3.x*yl.x + b3.y*yl.y;
  #pragma unroll
  for (int off = 32; off > 0; off >>= 1) {
    sq0 += __shfl_xor(sq0, off, 64); fm0 += __shfl_xor(fm0, off, 64);
    sq1 += __shfl_xor(sq1, off, 64); fm1 += __shfl_xor(fm1, off, 64);
    sq2 += __shfl_xor(sq2, off, 64); fm2 += __shfl_xor(fm2, off, 64);
    sq3 += __shfl_xor(sq3, off, 64); fm3 += __shfl_xor(fm3, off, 64);
  }
  if (l == 0) {
    float sgn = which ? 1.0f : -1.0f;
    float* var = out + TN*CC;                 // f_var half, base = Kxxd (k_features)
    atomicAdd(&var[(col0+0)*CC + c], sgn*sq0);
    atomicAdd(&var[(col0+1)*CC + c], sgn*sq1);
    atomicAdd(&var[(col0+2)*CC + c], sgn*sq2);
    atomicAdd(&var[(col0+3)*CC + c], sgn*sq3);
    if (which) {
      out[(col0+0)*CC + c] = fm0;
      out[(col0+1)*CC + c] = fm1;
      out[(col0+2)*CC + c] = fm2;
      out[(col0+3)*CC + c] = fm3;
    }
  }
}

extern "C" void kernel_launch(void* const* d_in, const int* in_sizes, int n_in,
                              void* d_out, int out_size, void* d_ws, size_t ws_size,
                              hipStream_t stream) {
  (void)in_sizes; (void)n_in; (void)out_size; (void)ws_size;
  const float* X  = (const float*)d_in[0];
  const float* Y  = (const float*)d_in[1];
  const float* Z  = (const float*)d_in[2];
  const float* Xt = (const float*)d_in[3];
  const float* W1 = (const float*)d_in[4];
  const float* b1 = (const float*)d_in[5];
  const float* W2 = (const float*)d_in[6];
  const float* b2 = (const float*)d_in[7];
  const float* W3 = (const float*)d_in[8];
  float* ws  = (float*)d_ws;
  float* out = (float*)d_out;

  float* XS   = ws + OFF_XS;
  float* A1   = ws + OFF_A1;
  float* A2   = ws + OFF_A2;
  float* G1   = ws + OFF_G1;
  float* G2   = ws + OFF_G2;
  float* W2T  = ws + OFF_W2T;
  float* Base = ws + OFF_BASE;
  float* Kzx  = ws + OFF_KZX;
  float* Kzz  = ws + OFF_KZZ;
  float* Kxz  = ws + OFF_KXZ;
  float* Kzzj = ws + OFF_KZZJ;
  float* KzzB = ws + OFF_KZZB;
  float* LamU = ws + OFF_LAMU;
  float* Lc   = ws + OFF_LC;
  float* invd = ws + OFF_INVD;
  float* ylam = ws + OFF_YLAM;

  k_w2t<<<128, 128, 0, stream>>>(W2, W2T, LamU);
  k_features<<<S_TOT, 128, 0, stream>>>(X, Z, Xt, W1, b1, W2, b2, W3, W2T, XS, A1, A2, G1, G2, out);
  k_base<<<dim3(16, 8, 3), 256, 0, stream>>>(XS, A1, A2, Base);
  k_gram<<<dim3(16, 8, 3*CC), 256, 0, stream>>>(G1, G2, Base, Y, Kzx, Kzz, Kxz, LamU);
  k_kzzb<<<dim3(8, 8, CC), 256, 0, stream>>>(Kzx, Kzz, Kzzj, KzzB);
  k_chol<<<2*CC, 512, 0, stream>>>(Kzzj, KzzB, Lc, invd, LamU, ylam);
  k_solve<<<8*CC, 512, 0, stream>>>(Lc, invd, ylam, Kxz, out);
}